// Round 1
// baseline (1338.465 us; speedup 1.0000x reference)
//
#include <hip/hip_runtime.h>
#include <hip/hip_bf16.h>
#include <cstdint>

#define NN 8192
#define DD 64

typedef __bf16 bf16x8 __attribute__((ext_vector_type(8)));
typedef float f32x16 __attribute__((ext_vector_type(16)));
typedef unsigned short u16;
typedef unsigned int u32;

__device__ __forceinline__ u16 f2bf(float f) {
    __hip_bfloat16 h = __float2bfloat16(f);
    return __builtin_bit_cast(u16, h);
}

// ---------------------------------------------------------------------------
// Big matmul: X1 = A_cl @ H_cl  (NC=64),  X2 = A_ue @ [H_ue | H_cl] (NC=128)
// Hp_* are bf16 H pre-packed in MFMA B-fragment order:
//   elem index = (kb*NC + col)*16 + half*8 + j  holds H[kb*16 + half*8 + j][col]
// Grid: (128, 4). blockIdx.x<64 -> cl, else ue. blockIdx.y = K-chunk (2048 k).
// Each wave: 32 rows x NC cols, accumulate over its K-chunk, atomicAdd out.
// ---------------------------------------------------------------------------
__global__ __launch_bounds__(256) void gnn_bigmm(
    const float* __restrict__ A_cl, const float* __restrict__ A_ue,
    const u16* __restrict__ Hp_cl, const u16* __restrict__ Hp_ue,
    float* __restrict__ X1, float* __restrict__ X2)
{
    const int bx = blockIdx.x;
    const int kc = blockIdx.y;
    const bool is_ue = bx >= 64;
    const int rbg = is_ue ? (bx - 64) : bx;
    const float* A = is_ue ? A_ue : A_cl;
    const u16* Hp = is_ue ? Hp_ue : Hp_cl;
    float* C = is_ue ? X2 : X1;
    const int NC = is_ue ? 128 : 64;
    const int NB = NC >> 5;           // 2 or 4 col-blocks of 32

    const int tid = threadIdx.x;
    const int w = tid >> 6;
    const int lane = tid & 63;
    const int m = lane & 31;
    const int half = lane >> 5;

    __shared__ float tile[128 * 18];  // 128 rows x 16 k, stride 18 (pad) = 9216B

    const int row0 = rbg * 128;
    const int kb0 = kc * 128;         // 128 kb-iterations of K=16

    f32x16 acc[4];
#pragma unroll
    for (int cb = 0; cb < 4; ++cb)
#pragma unroll
        for (int j = 0; j < 16; ++j) acc[cb][j] = 0.0f;

    const int4* HpV = (const int4*)Hp;

    // prefetch registers: 2 float4 per thread per tile (8KB tile / 256thr)
    float4 pf0, pf1;
    {
        int kb = kb0;
        int idx0 = tid, idx1 = 256 + tid;
        pf0 = *(const float4*)(A + (size_t)(row0 + (idx0 >> 2)) * NN + kb * 16 + (idx0 & 3) * 4);
        pf1 = *(const float4*)(A + (size_t)(row0 + (idx1 >> 2)) * NN + kb * 16 + (idx1 & 3) * 4);
    }

    for (int it = 0; it < 128; ++it) {
        __syncthreads();  // previous compute done before overwriting tile
        {
            int idx0 = tid, idx1 = 256 + tid;
            float* p0 = &tile[(idx0 >> 2) * 18 + (idx0 & 3) * 4];
            float* p1 = &tile[(idx1 >> 2) * 18 + (idx1 & 3) * 4];
            ((float2*)p0)[0] = make_float2(pf0.x, pf0.y);
            ((float2*)p0)[1] = make_float2(pf0.z, pf0.w);
            ((float2*)p1)[0] = make_float2(pf1.x, pf1.y);
            ((float2*)p1)[1] = make_float2(pf1.z, pf1.w);
        }
        __syncthreads();  // tile visible to all waves
        if (it + 1 < 128) {  // issue next tile's global loads early
            int kb = kb0 + it + 1;
            int idx0 = tid, idx1 = 256 + tid;
            pf0 = *(const float4*)(A + (size_t)(row0 + (idx0 >> 2)) * NN + kb * 16 + (idx0 & 3) * 4);
            pf1 = *(const float4*)(A + (size_t)(row0 + (idx1 >> 2)) * NN + kb * 16 + (idx1 & 3) * 4);
        }
        // A fragment: lane holds A[m][half*8 + j], j=0..7 (fp32 -> bf16)
        const float* ap = &tile[(w * 32 + m) * 18 + half * 8];
        bf16x8 af;
#pragma unroll
        for (int j = 0; j < 8; ++j) af[j] = (__bf16)ap[j];

        const int kb = kb0 + it;
#pragma unroll
        for (int cb = 0; cb < 4; ++cb) {
            if (cb < NB) {
                int col = cb * 32 + m;
                int4 braw = HpV[(kb * NC + col) * 2 + half];
                bf16x8 bfv = __builtin_bit_cast(bf16x8, braw);
                acc[cb] = __builtin_amdgcn_mfma_f32_32x32x16_bf16(af, bfv, acc[cb], 0, 0, 0);
            }
        }
    }

    // epilogue: C/D layout col=lane&31, row=(reg&3)+8*(reg>>2)+4*half
#pragma unroll
    for (int cb = 0; cb < 4; ++cb) {
        if (cb < NB) {
            int col = cb * 32 + m;
#pragma unroll
            for (int r = 0; r < 16; ++r) {
                int row = (r & 3) + 8 * (r >> 2) + 4 * half;
                unsafeAtomicAdd(&C[(size_t)(row0 + w * 32 + row) * NC + col], acc[cb][r]);
            }
        }
    }
}

// ---------------------------------------------------------------------------
// Small per-row layer: H_cl = relu(x1@w1+b1)+relu(x2@w2+b2), H_ue = relu(x3@w3+b3)
// fp32 compute; packs H into Hp_cl / Hp_ue (bf16, B-fragment order).
// LAST: instead computes pooled[c] += column-sums of H_cl (fp32 atomics).
// Block: 256 thr = 4 waves; wave cg owns cols [cg*16, cg*16+16); lane = row.
// Grid: 128 blocks x 64 rows.
// ---------------------------------------------------------------------------
template <int IN, bool LAST>
__global__ __launch_bounds__(256) void gnn_small(
    const float* __restrict__ x1, int ld1,
    const float* __restrict__ x2, int ld2,
    const float* __restrict__ x3, int ld3,
    const float* __restrict__ w1, const float* __restrict__ b1,
    const float* __restrict__ w2, const float* __restrict__ b2,
    const float* __restrict__ w3, const float* __restrict__ b3,
    u16* __restrict__ hp_cl, u16* __restrict__ hp_ue,
    float* __restrict__ pooled)
{
    const int tid = threadIdx.x;
    const int r = tid & 63;
    const int cg = __builtin_amdgcn_readfirstlane(tid >> 6);  // uniform -> s_load of w
    const int row0 = blockIdx.x * 64;
    const int row_g = row0 + r;

    __shared__ float xs[(IN == 64) ? 3 : 1][64][65];
    __shared__ u16 hbA[64][66];  // H_cl tile
    __shared__ u16 hbB[64][66];  // H_ue tile

    float xr[3][2];
    if (IN == 2) {
        float2 a = ((const float2*)x1)[row_g];
        float2 b = ((const float2*)x2)[row_g];
        float2 c = ((const float2*)x3)[row_g];
        xr[0][0] = a.x; xr[0][1] = a.y;
        xr[1][0] = b.x; xr[1][1] = b.y;
        xr[2][0] = c.x; xr[2][1] = c.y;
    } else {
#pragma unroll
        for (int mt = 0; mt < 3; ++mt) {
            if (LAST && mt == 2) break;
            const float* xp = (mt == 0) ? x1 : (mt == 1) ? x2 : x3;
            const int ld = (mt == 0) ? ld1 : (mt == 1) ? ld2 : ld3;
#pragma unroll
            for (int i = 0; i < 4; ++i) {
                int idx = i * 256 + tid;          // 0..1023
                int rl = idx >> 4;                // 0..63
                int c4 = (idx & 15) * 4;          // 0..60
                float4 v = *(const float4*)(xp + (size_t)(row0 + rl) * ld + c4);
                xs[mt][rl][c4 + 0] = v.x;
                xs[mt][rl][c4 + 1] = v.y;
                xs[mt][rl][c4 + 2] = v.z;
                xs[mt][rl][c4 + 3] = v.w;
            }
        }
        __syncthreads();
    }

    float a0[16], a1[16], a2[16];
#pragma unroll
    for (int j = 0; j < 16; ++j) {
        a0[j] = b1[cg * 16 + j];
        a1[j] = b2[cg * 16 + j];
        a2[j] = LAST ? 0.f : b3[cg * 16 + j];
    }
    for (int k = 0; k < IN; ++k) {
        float v0 = (IN == 2) ? xr[0][k] : xs[0][r][k];
        float v1 = (IN == 2) ? xr[1][k] : xs[1][r][k];
        float v2 = LAST ? 0.f : ((IN == 2) ? xr[2][k] : xs[2][r][k]);
        const float* w1r = w1 + k * 64 + cg * 16;
        const float* w2r = w2 + k * 64 + cg * 16;
        const float* w3r = w3 + k * 64 + cg * 16;
#pragma unroll
        for (int j = 0; j < 16; ++j) {
            a0[j] += v0 * w1r[j];
            a1[j] += v1 * w2r[j];
            if (!LAST) a2[j] += v2 * w3r[j];
        }
    }

    if (LAST) {
#pragma unroll
        for (int j = 0; j < 16; ++j) {
            float h = fmaxf(a0[j], 0.f) + fmaxf(a1[j], 0.f);
#pragma unroll
            for (int off = 32; off > 0; off >>= 1) h += __shfl_xor(h, off, 64);
            if (r == 0) unsafeAtomicAdd(&pooled[cg * 16 + j], h);
        }
    } else {
        // stage bf16 H tiles in LDS (stride 66 kills write bank conflicts)
#pragma unroll
        for (int j2 = 0; j2 < 8; ++j2) {
            float hc0 = fmaxf(a0[2 * j2], 0.f) + fmaxf(a1[2 * j2], 0.f);
            float hc1 = fmaxf(a0[2 * j2 + 1], 0.f) + fmaxf(a1[2 * j2 + 1], 0.f);
            float hu0 = fmaxf(a2[2 * j2], 0.f);
            float hu1 = fmaxf(a2[2 * j2 + 1], 0.f);
            u32 pc = (u32)f2bf(hc0) | ((u32)f2bf(hc1) << 16);
            u32 pu = (u32)f2bf(hu0) | ((u32)f2bf(hu1) << 16);
            *(u32*)&hbA[r][cg * 16 + 2 * j2] = pc;
            *(u32*)&hbB[r][cg * 16 + 2 * j2] = pu;
        }
        __syncthreads();
        // repack to global fragment order. 16B chunks: cl 512, ue 1024.
        for (int c = tid; c < 1536; c += 256) {
            int isue = (c >= 512) ? 1 : 0;
            int cc = isue ? (c - 512) : c;
            int halfc = cc & 1;
            int col, kb;
            if (!isue) { col = (cc >> 1) & 63; kb = cc >> 7; }
            else       { col = (cc >> 1) & 127; kb = cc >> 8; }
            u16 vals[8];
#pragma unroll
            for (int j = 0; j < 8; ++j) {
                int k = kb * 16 + halfc * 8 + j;
                u16 v;
                if (!isue) v = hbA[k][col];
                else v = (col < 64) ? hbB[k][col] : hbA[k][col - 64];
                vals[j] = v;
            }
            uint4 pk;
            pk.x = (u32)vals[0] | ((u32)vals[1] << 16);
            pk.y = (u32)vals[2] | ((u32)vals[3] << 16);
            pk.z = (u32)vals[4] | ((u32)vals[5] << 16);
            pk.w = (u32)vals[6] | ((u32)vals[7] << 16);
            u16* dst = isue ? hp_ue : hp_cl;
            int NCl = isue ? 128 : 64;
            int kbg = blockIdx.x * 4 + kb;
            *(uint4*)(dst + ((size_t)(kbg * NCl + col) * 16 + halfc * 8)) = pk;
        }
    }
}

// ---------------------------------------------------------------------------
// Head: out = relu(pooled @ Qw1 + Qb1) @ Qw2 + Qb2   (1 wave)
// ---------------------------------------------------------------------------
__global__ void gnn_head(const float* __restrict__ pooled,
                         const float* __restrict__ qw1, const float* __restrict__ qb1,
                         const float* __restrict__ qw2, const float* __restrict__ qb2,
                         float* __restrict__ out)
{
    int c = threadIdx.x;  // 0..63
    float acc = qb1[c];
    for (int k = 0; k < 64; ++k) acc += pooled[k] * qw1[k * 64 + c];
    float v = fmaxf(acc, 0.f) * qw2[c];
#pragma unroll
    for (int off = 32; off > 0; off >>= 1) v += __shfl_xor(v, off, 64);
    if (c == 0) out[0] = v + qb2[0];
}

extern "C" void kernel_launch(void* const* d_in, const int* in_sizes, int n_in,
                              void* d_out, int out_size, void* d_ws, size_t ws_size,
                              hipStream_t stream)
{
    const float* X_cl_1 = (const float*)d_in[0];
    const float* X_cl_2 = (const float*)d_in[1];
    const float* X_ue   = (const float*)d_in[2];
    const float* A_cl   = (const float*)d_in[3];
    const float* A_ue   = (const float*)d_in[4];
    const float* W1_w0  = (const float*)d_in[5];
    const float* W1_b0  = (const float*)d_in[6];
    const float* W1_w   = (const float*)d_in[7];
    const float* W1_b   = (const float*)d_in[8];
    const float* W2_w0  = (const float*)d_in[9];
    const float* W2_b0  = (const float*)d_in[10];
    const float* W2_w   = (const float*)d_in[11];
    const float* W2_b   = (const float*)d_in[12];
    const float* W3_w0  = (const float*)d_in[13];
    const float* W3_b0  = (const float*)d_in[14];
    const float* W3_w   = (const float*)d_in[15];
    const float* W3_b   = (const float*)d_in[16];
    const float* Q_w1   = (const float*)d_in[17];
    const float* Q_b1   = (const float*)d_in[18];
    const float* Q_w2   = (const float*)d_in[19];
    const float* Q_b2   = (const float*)d_in[20];

    char* ws = (char*)d_ws;
    u16*   Hp_cl  = (u16*)(ws);                       // 1 MB
    u16*   Hp_ue  = (u16*)(ws + (1 << 20));           // 2 MB
    float* X1     = (float*)(ws + 3ull * (1 << 20));  // 2 MB
    float* X2     = (float*)(ws + 5ull * (1 << 20));  // 4 MB
    float* pooled = (float*)(ws + 9ull * (1 << 20));  // 256 B

    dim3 blk(256);
    dim3 gsmall(128);
    dim3 gbig(128, 4);

    // layer 0 H (in-dim 2)
    gnn_small<2, false><<<gsmall, blk, 0, stream>>>(
        X_cl_1, 2, X_cl_2, 2, X_ue, 2,
        W1_w0, W1_b0, W2_w0, W2_b0, W3_w0, W3_b0, Hp_cl, Hp_ue, (float*)nullptr);

    for (int l = 0; l < 3; ++l) {
        hipMemsetAsync(X1, 0, (size_t)NN * 64 * 4, stream);
        hipMemsetAsync(X2, 0, (size_t)NN * 128 * 4, stream);
        gnn_bigmm<<<gbig, blk, 0, stream>>>(A_cl, A_ue, Hp_cl, Hp_ue, X1, X2);
        if (l < 2) {
            gnn_small<64, false><<<gsmall, blk, 0, stream>>>(
                X1, 64, X2, 128, X2 + 64, 128,
                W1_w + l * 4096, W1_b + l * 64,
                W2_w + l * 4096, W2_b + l * 64,
                W3_w + l * 4096, W3_b + l * 64,
                Hp_cl, Hp_ue, (float*)nullptr);
        } else {
            hipMemsetAsync(pooled, 0, 64 * 4, stream);
            gnn_small<64, true><<<gsmall, blk, 0, stream>>>(
                X1, 64, X2, 128, X2 + 64, 128,
                W1_w + 2 * 4096, W1_b + 2 * 64,
                W2_w + 2 * 4096, W2_b + 2 * 64,
                W3_w + 2 * 4096, W3_b + 2 * 64,
                Hp_cl, Hp_ue, pooled);
        }
    }
    gnn_head<<<dim3(1), dim3(64), 0, stream>>>(pooled, Q_w1, Q_b1, Q_w2, Q_b2, (float*)d_out);
}

// Round 2
// 1076.379 us; speedup vs baseline: 1.2435x; 1.2435x over previous
//
#include <hip/hip_runtime.h>
#include <hip/hip_bf16.h>
#include <cstdint>

#define NN 8192
#define DD 64

typedef __bf16 bf16x8 __attribute__((ext_vector_type(8)));
typedef float f32x16 __attribute__((ext_vector_type(16)));
typedef unsigned short u16;
typedef unsigned int u32;

__device__ __forceinline__ u16 f2bf(float f) {
    __hip_bfloat16 h = __float2bfloat16(f);
    return __builtin_bit_cast(u16, h);
}

// One K-step (16 k) worth of operands for one wave.
struct KB {
    float4 a0, a1;   // lane's A[row][k .. k+7] (half-selected)
    int4 b[4];       // B fragments for up to 4 col-blocks
};

__device__ __forceinline__ void loadKB(KB& f, const float* apL, const int4* bp,
                                       size_t bofs, int NB) {
    f.a0 = *(const float4*)(apL);
    f.a1 = *(const float4*)(apL + 4);
#pragma unroll
    for (int cb = 0; cb < 4; ++cb)
        if (cb < NB) f.b[cb] = bp[bofs + cb * 64];
}

__device__ __forceinline__ void computeKB(const KB& f, f32x16* acc, int NB) {
    bf16x8 af;
    af[0] = (__bf16)f.a0.x; af[1] = (__bf16)f.a0.y;
    af[2] = (__bf16)f.a0.z; af[3] = (__bf16)f.a0.w;
    af[4] = (__bf16)f.a1.x; af[5] = (__bf16)f.a1.y;
    af[6] = (__bf16)f.a1.z; af[7] = (__bf16)f.a1.w;
#pragma unroll
    for (int cb = 0; cb < 4; ++cb)
        if (cb < NB) {
            bf16x8 bfv = __builtin_bit_cast(bf16x8, f.b[cb]);
            acc[cb] = __builtin_amdgcn_mfma_f32_32x32x16_bf16(af, bfv, acc[cb], 0, 0, 0);
        }
}

// ---------------------------------------------------------------------------
// Big matmul: X1 = A_cl @ H_cl (NC=64), X2 = A_ue @ [H_ue | H_cl] (NC=128)
// Hp_*: bf16 H pre-packed in MFMA B-fragment order:
//   int4 index (kb*NC + col)*2 + half  holds H[kb*16+half*8 .. +7][col]
// Grid: 512 blocks x 256 thr. Even block -> cl, odd -> ue; rbg = bx>>1 gives
// the 32-row block. Each of the 4 waves streams K/4 = 2048 (128 ksteps of 16)
// with register double-buffering, NO barriers in the loop. Epilogue: 4-way
// LDS reduce + direct coalesced store (no atomics, no memset needed).
// ---------------------------------------------------------------------------
__global__ __launch_bounds__(256, 3) void gnn_bigmm(
    const float* __restrict__ A_cl, const float* __restrict__ A_ue,
    const u16* __restrict__ Hp_cl, const u16* __restrict__ Hp_ue,
    float* __restrict__ X1, float* __restrict__ X2)
{
    const int bx = blockIdx.x;
    const bool is_ue = bx & 1;
    const int rbg = bx >> 1;
    const float* A = is_ue ? A_ue : A_cl;
    const int4* HpV = (const int4*)(is_ue ? Hp_ue : Hp_cl);
    float* C = is_ue ? X2 : X1;
    const int NC = is_ue ? 128 : 64;
    const int NB = NC >> 5;

    const int tid = threadIdx.x;
    const int w = tid >> 6;
    const int lane = tid & 63;
    const int m = lane & 31;
    const int half = lane >> 5;

    const int row0 = rbg * 32;
    const int ks0 = w * 128;          // this wave's first kstep (of 512)

    __shared__ float red[32 * 128];   // 16 KB reduce buffer

    f32x16 acc[4];
#pragma unroll
    for (int cb = 0; cb < 4; ++cb)
#pragma unroll
        for (int j = 0; j < 16; ++j) acc[cb][j] = 0.0f;

    // lane's A base: row (row0+m), k offset ks0*16 + half*8
    const float* apL = A + (size_t)(row0 + m) * NN + ks0 * 16 + half * 8;
    // lane's B base in int4 units (col = cb*32 + m handled via +cb*64)
    const int4* bp = HpV + (m * 2 + half);

    KB f0, f1;
    loadKB(f0, apL, bp, (size_t)ks0 * NC * 2, NB);
    for (int s = 0; s < 128; s += 2) {
        loadKB(f1, apL + (size_t)(s + 1) * 16, bp, (size_t)(ks0 + s + 1) * NC * 2, NB);
        computeKB(f0, acc, NB);
        if (s + 2 < 128)
            loadKB(f0, apL + (size_t)(s + 2) * 16, bp, (size_t)(ks0 + s + 2) * NC * 2, NB);
        computeKB(f1, acc, NB);
    }

    // 4-way deterministic LDS reduce (C/D layout: col=m, row=(r&3)+8*(r>>2)+4*half)
    for (int wv = 0; wv < 4; ++wv) {
        if (w == wv) {
#pragma unroll
            for (int cb = 0; cb < 4; ++cb)
                if (cb < NB) {
                    int col = cb * 32 + m;
#pragma unroll
                    for (int r = 0; r < 16; ++r) {
                        int row = (r & 3) + 8 * (r >> 2) + 4 * half;
                        float* p = &red[row * NC + col];
                        if (wv == 0) *p = acc[cb][r];
                        else *p += acc[cb][r];
                    }
                }
        }
        __syncthreads();
    }

    // coalesced store of the 32 x NC tile
    float4* dst = (float4*)(C + (size_t)row0 * NC);
    const float4* src = (const float4*)red;
    const int nv = (32 * NC) >> 2;
    for (int i = tid; i < nv; i += 256) dst[i] = src[i];
}

// ---------------------------------------------------------------------------
// Small per-row layer: H_cl = relu(x1@w1+b1)+relu(x2@w2+b2), H_ue = relu(x3@w3+b3)
// fp32 compute; packs H into Hp_cl / Hp_ue (bf16, B-fragment order).
// LAST: instead computes pooled[c] += column-sums of H_cl (fp32 atomics).
// IN==2 instantiation also zeroes pooled (runs strictly before LAST).
// ---------------------------------------------------------------------------
template <int IN, bool LAST>
__global__ __launch_bounds__(256) void gnn_small(
    const float* __restrict__ x1, int ld1,
    const float* __restrict__ x2, int ld2,
    const float* __restrict__ x3, int ld3,
    const float* __restrict__ w1, const float* __restrict__ b1,
    const float* __restrict__ w2, const float* __restrict__ b2,
    const float* __restrict__ w3, const float* __restrict__ b3,
    u16* __restrict__ hp_cl, u16* __restrict__ hp_ue,
    float* __restrict__ pooled)
{
    const int tid = threadIdx.x;
    const int r = tid & 63;
    const int cg = __builtin_amdgcn_readfirstlane(tid >> 6);
    const int row0 = blockIdx.x * 64;
    const int row_g = row0 + r;

    if (IN == 2 && !LAST) {
        if (blockIdx.x == 0 && tid < 64 && pooled) pooled[tid] = 0.0f;
    }

    __shared__ float xs[(IN == 64) ? 3 : 1][64][65];
    __shared__ u16 hbA[64][66];
    __shared__ u16 hbB[64][66];

    float xr[3][2];
    if (IN == 2) {
        float2 a = ((const float2*)x1)[row_g];
        float2 b = ((const float2*)x2)[row_g];
        float2 c = ((const float2*)x3)[row_g];
        xr[0][0] = a.x; xr[0][1] = a.y;
        xr[1][0] = b.x; xr[1][1] = b.y;
        xr[2][0] = c.x; xr[2][1] = c.y;
    } else {
#pragma unroll
        for (int mt = 0; mt < 3; ++mt) {
            if (LAST && mt == 2) break;
            const float* xp = (mt == 0) ? x1 : (mt == 1) ? x2 : x3;
            const int ld = (mt == 0) ? ld1 : (mt == 1) ? ld2 : ld3;
#pragma unroll
            for (int i = 0; i < 4; ++i) {
                int idx = i * 256 + tid;
                int rl = idx >> 4;
                int c4 = (idx & 15) * 4;
                float4 v = *(const float4*)(xp + (size_t)(row0 + rl) * ld + c4);
                xs[mt][rl][c4 + 0] = v.x;
                xs[mt][rl][c4 + 1] = v.y;
                xs[mt][rl][c4 + 2] = v.z;
                xs[mt][rl][c4 + 3] = v.w;
            }
        }
        __syncthreads();
    }

    float a0[16], a1[16], a2[16];
#pragma unroll
    for (int j = 0; j < 16; ++j) {
        a0[j] = b1[cg * 16 + j];
        a1[j] = b2[cg * 16 + j];
        a2[j] = LAST ? 0.f : b3[cg * 16 + j];
    }
    for (int k = 0; k < IN; ++k) {
        float v0 = (IN == 2) ? xr[0][k] : xs[0][r][k];
        float v1 = (IN == 2) ? xr[1][k] : xs[1][r][k];
        float v2 = LAST ? 0.f : ((IN == 2) ? xr[2][k] : xs[2][r][k]);
        const float* w1r = w1 + k * 64 + cg * 16;
        const float* w2r = w2 + k * 64 + cg * 16;
        const float* w3r = w3 + k * 64 + cg * 16;
#pragma unroll
        for (int j = 0; j < 16; ++j) {
            a0[j] += v0 * w1r[j];
            a1[j] += v1 * w2r[j];
            if (!LAST) a2[j] += v2 * w3r[j];
        }
    }

    if (LAST) {
#pragma unroll
        for (int j = 0; j < 16; ++j) {
            float h = fmaxf(a0[j], 0.f) + fmaxf(a1[j], 0.f);
#pragma unroll
            for (int off = 32; off > 0; off >>= 1) h += __shfl_xor(h, off, 64);
            if (r == 0) unsafeAtomicAdd(&pooled[cg * 16 + j], h);
        }
    } else {
#pragma unroll
        for (int j2 = 0; j2 < 8; ++j2) {
            float hc0 = fmaxf(a0[2 * j2], 0.f) + fmaxf(a1[2 * j2], 0.f);
            float hc1 = fmaxf(a0[2 * j2 + 1], 0.f) + fmaxf(a1[2 * j2 + 1], 0.f);
            float hu0 = fmaxf(a2[2 * j2], 0.f);
            float hu1 = fmaxf(a2[2 * j2 + 1], 0.f);
            u32 pc = (u32)f2bf(hc0) | ((u32)f2bf(hc1) << 16);
            u32 pu = (u32)f2bf(hu0) | ((u32)f2bf(hu1) << 16);
            *(u32*)&hbA[r][cg * 16 + 2 * j2] = pc;
            *(u32*)&hbB[r][cg * 16 + 2 * j2] = pu;
        }
        __syncthreads();
        for (int c = tid; c < 1536; c += 256) {
            int isue = (c >= 512) ? 1 : 0;
            int cc = isue ? (c - 512) : c;
            int halfc = cc & 1;
            int col, kb;
            if (!isue) { col = (cc >> 1) & 63; kb = cc >> 7; }
            else       { col = (cc >> 1) & 127; kb = cc >> 8; }
            u16 vals[8];
#pragma unroll
            for (int j = 0; j < 8; ++j) {
                int k = kb * 16 + halfc * 8 + j;
                u16 v;
                if (!isue) v = hbA[k][col];
                else v = (col < 64) ? hbB[k][col] : hbA[k][col - 64];
                vals[j] = v;
            }
            uint4 pk;
            pk.x = (u32)vals[0] | ((u32)vals[1] << 16);
            pk.y = (u32)vals[2] | ((u32)vals[3] << 16);
            pk.z = (u32)vals[4] | ((u32)vals[5] << 16);
            pk.w = (u32)vals[6] | ((u32)vals[7] << 16);
            u16* dst = isue ? hp_ue : hp_cl;
            int NCl = isue ? 128 : 64;
            int kbg = blockIdx.x * 4 + kb;
            *(uint4*)(dst + ((size_t)(kbg * NCl + col) * 16 + halfc * 8)) = pk;
        }
    }
}

// ---------------------------------------------------------------------------
// Head: out = relu(pooled @ Qw1 + Qb1) @ Qw2 + Qb2   (1 wave)
// ---------------------------------------------------------------------------
__global__ void gnn_head(const float* __restrict__ pooled,
                         const float* __restrict__ qw1, const float* __restrict__ qb1,
                         const float* __restrict__ qw2, const float* __restrict__ qb2,
                         float* __restrict__ out)
{
    int c = threadIdx.x;
    float acc = qb1[c];
    for (int k = 0; k < 64; ++k) acc += pooled[k] * qw1[k * 64 + c];
    float v = fmaxf(acc, 0.f) * qw2[c];
#pragma unroll
    for (int off = 32; off > 0; off >>= 1) v += __shfl_xor(v, off, 64);
    if (c == 0) out[0] = v + qb2[0];
}

extern "C" void kernel_launch(void* const* d_in, const int* in_sizes, int n_in,
                              void* d_out, int out_size, void* d_ws, size_t ws_size,
                              hipStream_t stream)
{
    const float* X_cl_1 = (const float*)d_in[0];
    const float* X_cl_2 = (const float*)d_in[1];
    const float* X_ue   = (const float*)d_in[2];
    const float* A_cl   = (const float*)d_in[3];
    const float* A_ue   = (const float*)d_in[4];
    const float* W1_w0  = (const float*)d_in[5];
    const float* W1_b0  = (const float*)d_in[6];
    const float* W1_w   = (const float*)d_in[7];
    const float* W1_b   = (const float*)d_in[8];
    const float* W2_w0  = (const float*)d_in[9];
    const float* W2_b0  = (const float*)d_in[10];
    const float* W2_w   = (const float*)d_in[11];
    const float* W2_b   = (const float*)d_in[12];
    const float* W3_w0  = (const float*)d_in[13];
    const float* W3_b0  = (const float*)d_in[14];
    const float* W3_w   = (const float*)d_in[15];
    const float* W3_b   = (const float*)d_in[16];
    const float* Q_w1   = (const float*)d_in[17];
    const float* Q_b1   = (const float*)d_in[18];
    const float* Q_w2   = (const float*)d_in[19];
    const float* Q_b2   = (const float*)d_in[20];

    char* ws = (char*)d_ws;
    u16*   Hp_cl  = (u16*)(ws);                       // 1 MB
    u16*   Hp_ue  = (u16*)(ws + (1 << 20));           // 2 MB
    float* X1     = (float*)(ws + 3ull * (1 << 20));  // 2 MB
    float* X2     = (float*)(ws + 5ull * (1 << 20));  // 4 MB
    float* pooled = (float*)(ws + 9ull * (1 << 20));  // 256 B

    dim3 blk(256);
    dim3 gsmall(128);
    dim3 gbig(512);

    gnn_small<2, false><<<gsmall, blk, 0, stream>>>(
        X_cl_1, 2, X_cl_2, 2, X_ue, 2,
        W1_w0, W1_b0, W2_w0, W2_b0, W3_w0, W3_b0, Hp_cl, Hp_ue, pooled);

    for (int l = 0; l < 3; ++l) {
        gnn_bigmm<<<gbig, blk, 0, stream>>>(A_cl, A_ue, Hp_cl, Hp_ue, X1, X2);
        if (l < 2) {
            gnn_small<64, false><<<gsmall, blk, 0, stream>>>(
                X1, 64, X2, 128, X2 + 64, 128,
                W1_w + l * 4096, W1_b + l * 64,
                W2_w + l * 4096, W2_b + l * 64,
                W3_w + l * 4096, W3_b + l * 64,
                Hp_cl, Hp_ue, (float*)nullptr);
        } else {
            gnn_small<64, true><<<gsmall, blk, 0, stream>>>(
                X1, 64, X2, 128, X2 + 64, 128,
                W1_w + 2 * 4096, W1_b + 2 * 64,
                W2_w + 2 * 4096, W2_b + 2 * 64,
                W3_w + 2 * 4096, W3_b + 2 * 64,
                Hp_cl, Hp_ue, pooled);
        }
    }
    gnn_head<<<dim3(1), dim3(64), 0, stream>>>(pooled, Q_w1, Q_b1, Q_w2, Q_b2, (float*)d_out);
}